// Round 1
// baseline (466.278 us; speedup 1.0000x reference)
//
#include <hip/hip_runtime.h>

// grid_sample bilinear, zeros padding, align_corners=False
// img:  [16, 1, 1024, 1024] f32
// grid: [16, 1024, 1024, 2] f32 (x, y) in [-1, 1] (slightly beyond)
// out:  [16, 1, 1024, 1024] f32

constexpr int NB = 16;
constexpr int H = 1024;
constexpr int W = 1024;
constexpr long long TOTAL = (long long)NB * H * W;  // 16,777,216

__global__ __launch_bounds__(256) void ESMGridSample_kernel(
    const float* __restrict__ img,
    const float* __restrict__ grid,
    float* __restrict__ out)
{
    long long tid = (long long)blockIdx.x * blockDim.x + threadIdx.x;
    long long p4 = tid * 4;  // first of 4 consecutive output pixels
    if (p4 >= TOTAL) return;

    int n = (int)(p4 >> 20);  // H*W = 2^20 pixels per batch
    const float* __restrict__ imgn = img + ((long long)n << 20);

    // grid is [..., 2]: 4 pixels -> 8 floats -> two float4 loads
    const float4* g4 = (const float4*)(grid + (p4 << 1));
    float4 ga = g4[0];
    float4 gb = g4[1];

    float gx[4] = {ga.x, ga.z, gb.x, gb.z};
    float gy[4] = {ga.y, ga.w, gb.y, gb.w};
    float res[4];

#pragma unroll
    for (int i = 0; i < 4; ++i) {
        float ix = (gx[i] + 1.0f) * (W * 0.5f) - 0.5f;
        float iy = (gy[i] + 1.0f) * (H * 0.5f) - 0.5f;
        float x0f = floorf(ix);
        float y0f = floorf(iy);
        float wx = ix - x0f;
        float wy = iy - y0f;
        int x0 = (int)x0f;
        int y0 = (int)y0f;
        int x1 = x0 + 1;
        int y1 = y0 + 1;

        // validity masks (zeros padding)
        float vx0 = (x0 >= 0 && x0 < W) ? 1.0f : 0.0f;
        float vx1 = (x1 >= 0 && x1 < W) ? 1.0f : 0.0f;
        float vy0 = (y0 >= 0 && y0 < H) ? 1.0f : 0.0f;
        float vy1 = (y1 >= 0 && y1 < H) ? 1.0f : 0.0f;

        // clamped indices so loads are always in-bounds (branchless)
        int cx0 = min(max(x0, 0), W - 1);
        int cx1 = min(max(x1, 0), W - 1);
        int cy0 = min(max(y0, 0), H - 1);
        int cy1 = min(max(y1, 0), H - 1);

        float v00 = imgn[cy0 * W + cx0] * (vx0 * vy0);
        float v01 = imgn[cy0 * W + cx1] * (vx1 * vy0);
        float v10 = imgn[cy1 * W + cx0] * (vx0 * vy1);
        float v11 = imgn[cy1 * W + cx1] * (vx1 * vy1);

        res[i] = v00 * (1.0f - wx) * (1.0f - wy)
               + v01 * wx * (1.0f - wy)
               + v10 * (1.0f - wx) * wy
               + v11 * wx * wy;
    }

    float4 o = make_float4(res[0], res[1], res[2], res[3]);
    *(float4*)(out + p4) = o;
}

extern "C" void kernel_launch(void* const* d_in, const int* in_sizes, int n_in,
                              void* d_out, int out_size, void* d_ws, size_t ws_size,
                              hipStream_t stream) {
    const float* img  = (const float*)d_in[0];  // source_depth
    const float* grid = (const float*)d_in[1];  // pr
    // d_in[2] = gt_map (unused by reference output)
    float* out = (float*)d_out;

    const long long n_threads = TOTAL / 4;           // 4,194,304
    const int block = 256;
    const long long n_blocks = (n_threads + block - 1) / block;  // 16,384

    ESMGridSample_kernel<<<(dim3)(unsigned)n_blocks, block, 0, stream>>>(img, grid, out);
}